// Round 9
// baseline (63.302 us; speedup 1.0000x reference)
//
#include <hip/hip_runtime.h>

// Problem constants: B=2, S=4, N=M=4096, fp32 3D points.
constexpr int Sn = 4;
constexpr int Nn = 4096;
constexpr int Mn = 4096;
constexpr int NS2 = 16;               // (dir,slice): z = dir*8 + slice
constexpr int CH  = 16;               // combine-kernel i-range split
constexpr int APT = 8;                // A-points per thread

// ws: float4 tB[NS2][Mn] (1 MB) | float pmin[NS2][NBC][Nn] | float sums2[NS2][CH]
constexpr size_t TB_FLOAT4S = (size_t)NS2 * Mn;

#define RL(x, k) __int_as_float(__builtin_amdgcn_readlane(__float_as_int(x), (k)))

// ---- prep: transformed B table (-2bx,-2by,-2bz,|b|^2). z<8 from Y, z>=8 from X.
__global__ __launch_bounds__(256) void chamfer_prep(
    const float* __restrict__ X, const float* __restrict__ Y,
    float4* __restrict__ tB)
{
    const int idx = blockIdx.x * 256 + threadIdx.x;   // 0..65535
    const int z = idx >> 12;
    const int m = idx & (Mn - 1);
    const float* src = (z < 8) ? (Y + (size_t)z * (Mn * 3))
                               : (X + (size_t)(z - 8) * (Mn * 3));
    const float bx = src[m * 3 + 0];
    const float by = src[m * 3 + 1];
    const float bz = src[m * 3 + 2];
    tB[idx] = make_float4(-2.0f * bx, -2.0f * by, -2.0f * bz,
                          bx * bx + by * by + bz * bz);
}

// ---- partial: NO LDS, NO DS. B-points held per-lane in VGPRs; broadcast via
// v_readlane (VALU pipe, compile-time lane index). One coalesced dwordx4 load
// per wave per 64 B-points.
template <int NBC>
__global__ __launch_bounds__(256) void chamfer_partial(
    const float* __restrict__ X,
    const float* __restrict__ Y,
    const float4* __restrict__ tB,
    float* __restrict__ pmin)      // [NS2][NBC][Nn]
{
    constexpr int BCHUNK = Mn / NBC;
    constexpr int ATILE  = APT * 256;

    const int at    = blockIdx.x;
    const int bc    = blockIdx.y;
    const int z     = blockIdx.z;
    const int slice = z & 7;
    const int dir   = z >> 3;
    const int tid   = threadIdx.x;
    const int lane  = tid & 63;

    const float* A = (dir == 0 ? X : Y) + (size_t)slice * (Nn * 3);
    const float4* __restrict__ tb = tB + (size_t)z * Mn + (size_t)bc * BCHUNK;

    // Register-block APT A-points (strided ownership: n = at*ATILE + j*256 + tid).
    float ax[APT], ay[APT], az[APT], acc[APT];
    #pragma unroll
    for (int j = 0; j < APT; ++j) {
        const int n = at * ATILE + j * 256 + tid;
        ax[j] = A[n * 3 + 0];
        ay[j] = A[n * 3 + 1];
        az[j] = A[n * 3 + 2];
        acc[j] = 3.4e38f;
    }

    // Scan B in 64-point sub-chunks: lane l holds point l in a float4 reg.
    for (int sc = 0; sc < BCHUNK / 64; ++sc) {
        const float4 br = tb[sc * 64 + lane];    // one dwordx4 per wave

        #pragma unroll
        for (int k = 0; k < 64; k += 2) {
            const float bx0 = RL(br.x, k),     by0 = RL(br.y, k);
            const float bz0 = RL(br.z, k),     bw0 = RL(br.w, k);
            const float bx1 = RL(br.x, k + 1), by1 = RL(br.y, k + 1);
            const float bz1 = RL(br.z, k + 1), bw1 = RL(br.w, k + 1);
            #pragma unroll
            for (int j = 0; j < APT; ++j) {
                float d0 = fmaf(ax[j], bx0, fmaf(ay[j], by0, fmaf(az[j], bz0, bw0)));
                float d1 = fmaf(ax[j], bx1, fmaf(ay[j], by1, fmaf(az[j], bz1, bw1)));
                acc[j] = fminf(fminf(acc[j], d0), d1);   // -> v_min3_f32
            }
        }
    }

    // Coalesced store of partial mins (+|a|^2 recomputed; constant across chunks)
    float* dst = pmin + ((size_t)z * NBC + bc) * Nn + at * ATILE;
    #pragma unroll
    for (int j = 0; j < APT; ++j) {
        const float a2 = ax[j] * ax[j] + ay[j] * ay[j] + az[j] * az[j];
        dst[j * 256 + tid] = acc[j] + a2;
    }
}

template <int NBC>
__global__ __launch_bounds__(256) void chamfer_combine(
    const float* __restrict__ pmin, float* __restrict__ sums2)  // sums2[NS2][CH]
{
    const int z   = blockIdx.x;       // 0..15
    const int c   = blockIdx.y;       // 0..CH-1
    const int tid = threadIdx.x;
    constexpr int SPAN = Nn / CH;     // 256

    const float* p = pmin + (size_t)z * NBC * Nn;

    float s = 0.0f;
    for (int i = c * SPAN + tid; i < (c + 1) * SPAN; i += 256) {
        float m = p[i];
        #pragma unroll 8
        for (int bc = 1; bc < NBC; ++bc) m = fminf(m, p[(size_t)bc * Nn + i]);
        s += m;
    }

    s += __shfl_down(s, 32);
    s += __shfl_down(s, 16);
    s += __shfl_down(s, 8);
    s += __shfl_down(s, 4);
    s += __shfl_down(s, 2);
    s += __shfl_down(s, 1);

    __shared__ float red[4];
    if ((tid & 63) == 0) red[tid >> 6] = s;
    __syncthreads();
    if (tid == 0) sums2[z * CH + c] = red[0] + red[1] + red[2] + red[3];
}

__global__ __launch_bounds__(64) void chamfer_finalize(
    const float* __restrict__ sums2, float* __restrict__ out)
{
    const int tid = threadIdx.x;
    // total[z] = sum_c sums2[z][c]; z = dir*8 + (b*4 + s)
    __shared__ float tot[NS2];
    if (tid < NS2) {
        float t = 0.0f;
        #pragma unroll
        for (int c = 0; c < CH; ++c) t += sums2[tid * CH + c];
        tot[tid] = t;
    }
    __syncthreads();
    if (tid < 8) {
        const int s = tid >> 1, b = tid & 1;
        const int l = b * Sn + s;
        out[4 + s * 2 + b] = tot[l] * (1.0f / Nn) + tot[8 + l] * (1.0f / Mn);
    } else if (tid < 12) {
        const int s = tid - 8;
        float c0 = tot[0 * Sn + s] * (1.0f / Nn) + tot[8 + 0 * Sn + s] * (1.0f / Mn);
        float c1 = tot[1 * Sn + s] * (1.0f / Nn) + tot[8 + 1 * Sn + s] * (1.0f / Mn);
        out[s] = 0.5f * (c0 + c1);
    }
}

extern "C" void kernel_launch(void* const* d_in, const int* in_sizes, int n_in,
                              void* d_out, int out_size, void* d_ws, size_t ws_size,
                              hipStream_t stream) {
    const float* X = (const float*)d_in[0];   // output_points [2,4,4096,3]
    const float* Y = (const float*)d_in[1];   // target_points [2,4,4096,3]
    float* out = (float*)d_out;               // 12 floats

    float4* tB   = (float4*)d_ws;                     // 1 MB
    float*  pmin = (float*)d_ws + 4 * TB_FLOAT4S;

    chamfer_prep<<<NS2 * Mn / 256, 256, 0, stream>>>(X, Y, tB);

    const size_t need_main = (4 * TB_FLOAT4S + (size_t)NS2 * 64 * Nn + 512) * sizeof(float);

    if (ws_size >= need_main) {
        // NBC=64: grid (2,64,16)=2048 blocks (8/CU, 8 waves/SIMD), pmin 16 MB.
        constexpr int NBC = 64;
        float* sums2 = pmin + (size_t)NS2 * NBC * Nn;
        dim3 grid(Nn / (APT * 256), NBC, NS2);
        chamfer_partial<NBC><<<grid, 256, 0, stream>>>(X, Y, tB, pmin);
        chamfer_combine<NBC><<<dim3(NS2, CH), 256, 0, stream>>>(pmin, sums2);
        chamfer_finalize<<<1, 64, 0, stream>>>(sums2, out);
    } else {
        // Small-ws fallback: NBC=8 (pmin 2 MB), same code path (sc-loop longer).
        constexpr int NBC = 8;
        float* sums2 = pmin + (size_t)NS2 * NBC * Nn;
        dim3 grid(Nn / (APT * 256), NBC, NS2);
        chamfer_partial<NBC><<<grid, 256, 0, stream>>>(X, Y, tB, pmin);
        chamfer_combine<NBC><<<dim3(NS2, CH), 256, 0, stream>>>(pmin, sums2);
        chamfer_finalize<<<1, 64, 0, stream>>>(sums2, out);
    }
}

// Round 10
// 48.224 us; speedup vs baseline: 1.3127x; 1.3127x over previous
//
#include <hip/hip_runtime.h>

// Problem constants: B=2, S=4, N=M=4096, fp32 3D points.
constexpr int Sn = 4;
constexpr int Nn = 4096;
constexpr int Mn = 4096;
constexpr int NS2 = 16;               // (dir,slice): z = dir*8 + slice
constexpr int CH  = 16;               // combine-kernel i-range split

// ws layout: float pmin[NS2][NBC][Nn] | float sums2[NS2][CH]

template <int APT, int NBC, int UNR>
__global__ __launch_bounds__(256) void chamfer_partial(
    const float* __restrict__ X,   // output_points [8][4096][3]
    const float* __restrict__ Y,   // target_points [8][4096][3]
    float* __restrict__ pmin)      // [NS2][NBC][Nn]
{
    constexpr int BCHUNK = Mn / NBC;
    constexpr int ATILE  = APT * 256;

    __shared__ float4 ldsB[BCHUNK];

    const int at    = blockIdx.x;
    const int bc    = blockIdx.y;
    const int z     = blockIdx.z;
    const int slice = z & 7;
    const int dir   = z >> 3;
    const int tid   = threadIdx.x;

    const float* A  = (dir == 0 ? X : Y) + (size_t)slice * (Nn * 3);
    const float* Bp = (dir == 0 ? Y : X) + (size_t)slice * (Mn * 3) + bc * (BCHUNK * 3);

    // Register-block APT A-points (strided ownership: n = at*ATILE + j*256 + tid).
    float ax[APT], ay[APT], az[APT], acc[APT];
    #pragma unroll
    for (int j = 0; j < APT; ++j) {
        const int n = at * ATILE + j * 256 + tid;
        ax[j] = A[n * 3 + 0];
        ay[j] = A[n * 3 + 1];
        az[j] = A[n * 3 + 2];
        acc[j] = 3.4e38f;
    }

    // Stage B chunk pre-transformed: (-2bx, -2by, -2bz, |b|^2)
    for (int p = tid; p < BCHUNK; p += 256) {
        float bx = Bp[p * 3 + 0], by = Bp[p * 3 + 1], bz = Bp[p * 3 + 2];
        ldsB[p] = make_float4(-2.0f * bx, -2.0f * by, -2.0f * bz,
                              bx * bx + by * by + bz * bz);
    }
    __syncthreads();

    // 2 ds_read_b128 broadcasts amortized over 2*APT pairs;
    // 3 FMA per pair + v_min3 per 2 pairs. UNR=2 keeps b-liveness modest.
    #pragma unroll UNR
    for (int m = 0; m < BCHUNK; m += 2) {
        const float4 b0 = ldsB[m + 0];
        const float4 b1 = ldsB[m + 1];
        #pragma unroll
        for (int j = 0; j < APT; ++j) {
            float d0 = fmaf(ax[j], b0.x, fmaf(ay[j], b0.y, fmaf(az[j], b0.z, b0.w)));
            float d1 = fmaf(ax[j], b1.x, fmaf(ay[j], b1.y, fmaf(az[j], b1.z, b1.w)));
            acc[j] = fminf(fminf(acc[j], d0), d1);   // -> v_min3_f32
        }
    }

    // Coalesced store of partial mins (+|a|^2 recomputed; constant across chunks)
    float* dst = pmin + ((size_t)z * NBC + bc) * Nn + at * ATILE;
    #pragma unroll
    for (int j = 0; j < APT; ++j) {
        const float a2 = ax[j] * ax[j] + ay[j] * ay[j] + az[j] * az[j];
        dst[j * 256 + tid] = acc[j] + a2;
    }
}

template <int NBC>
__global__ __launch_bounds__(256) void chamfer_combine(
    const float* __restrict__ pmin, float* __restrict__ sums2)  // sums2[NS2][CH]
{
    const int z   = blockIdx.x;       // 0..15
    const int c   = blockIdx.y;       // 0..CH-1
    const int tid = threadIdx.x;
    constexpr int SPAN = Nn / CH;     // 256

    const float* p = pmin + (size_t)z * NBC * Nn;

    float s = 0.0f;
    for (int i = c * SPAN + tid; i < (c + 1) * SPAN; i += 256) {
        float m = p[i];
        #pragma unroll 8
        for (int bc = 1; bc < NBC; ++bc) m = fminf(m, p[(size_t)bc * Nn + i]);
        s += m;
    }

    s += __shfl_down(s, 32);
    s += __shfl_down(s, 16);
    s += __shfl_down(s, 8);
    s += __shfl_down(s, 4);
    s += __shfl_down(s, 2);
    s += __shfl_down(s, 1);

    __shared__ float red[4];
    if ((tid & 63) == 0) red[tid >> 6] = s;
    __syncthreads();
    if (tid == 0) sums2[z * CH + c] = red[0] + red[1] + red[2] + red[3];
}

__global__ __launch_bounds__(64) void chamfer_finalize(
    const float* __restrict__ sums2, float* __restrict__ out)
{
    const int tid = threadIdx.x;
    // total[z] = sum_c sums2[z][c]; z = dir*8 + (b*4 + s)
    __shared__ float tot[NS2];
    if (tid < NS2) {
        float t = 0.0f;
        #pragma unroll
        for (int c = 0; c < CH; ++c) t += sums2[tid * CH + c];
        tot[tid] = t;
    }
    __syncthreads();
    if (tid < 8) {
        const int s = tid >> 1, b = tid & 1;
        const int l = b * Sn + s;
        out[4 + s * 2 + b] = tot[l] * (1.0f / Nn) + tot[8 + l] * (1.0f / Mn);
    } else if (tid < 12) {
        const int s = tid - 8;
        float c0 = tot[0 * Sn + s] * (1.0f / Nn) + tot[8 + 0 * Sn + s] * (1.0f / Mn);
        float c1 = tot[1 * Sn + s] * (1.0f / Nn) + tot[8 + 1 * Sn + s] * (1.0f / Mn);
        out[s] = 0.5f * (c0 + c1);
    }
}

extern "C" void kernel_launch(void* const* d_in, const int* in_sizes, int n_in,
                              void* d_out, int out_size, void* d_ws, size_t ws_size,
                              hipStream_t stream) {
    const float* X = (const float*)d_in[0];   // output_points [2,4,4096,3]
    const float* Y = (const float*)d_in[1];   // target_points [2,4,4096,3]
    float* out  = (float*)d_out;              // 12 floats
    float* pmin = (float*)d_ws;

    const size_t need_main = ((size_t)NS2 * 64 * Nn + NS2 * CH + 64) * sizeof(float);

    if (ws_size >= need_main) {
        // APT=16, NBC=64 (BCHUNK=64): DS traffic halved vs anchor, grid
        // (1,64,16)=1024 blocks = 4/CU. No min-waves cap (R4/R5 lesson),
        // unroll 2 (<=4 live b-float4) -> ~100 VGPR, natural 4 waves/SIMD.
        constexpr int APT = 16, NBC = 64;
        float* sums2 = pmin + (size_t)NS2 * NBC * Nn;
        dim3 grid(Nn / (APT * 256), NBC, NS2);
        chamfer_partial<APT, NBC, 2><<<grid, 256, 0, stream>>>(X, Y, pmin);
        chamfer_combine<NBC><<<dim3(NS2, CH), 256, 0, stream>>>(pmin, sums2);
        chamfer_finalize<<<1, 64, 0, stream>>>(sums2, out);
    } else {
        // Small-ws fallback: R3 anchor geometry (APT=8, NBC=32, unroll 4).
        constexpr int APT = 8, NBC = 32;
        float* sums2 = pmin + (size_t)NS2 * NBC * Nn;
        dim3 grid(Nn / (APT * 256), NBC, NS2);
        chamfer_partial<APT, NBC, 4><<<grid, 256, 0, stream>>>(X, Y, pmin);
        chamfer_combine<NBC><<<dim3(NS2, CH), 256, 0, stream>>>(pmin, sums2);
        chamfer_finalize<<<1, 64, 0, stream>>>(sums2, out);
    }
}

// Round 11
// 36.756 us; speedup vs baseline: 1.7222x; 1.3120x over previous
//
#include <hip/hip_runtime.h>

// Problem constants: B=2, S=4, N=M=4096, fp32 3D points.
constexpr int Sn = 4;
constexpr int Nn = 4096;
constexpr int Mn = 4096;
constexpr int NS2 = 16;               // (dir,slice): z = dir*8 + slice
constexpr int APT = 8;                // R3-proven
constexpr int NBC = 32;               // R3-proven
constexpr int BCHUNK = Mn / NBC;      // 128

// ws layout: uint rowmin[NS2][Nn] (256 KB) | float sums[NS2]

__global__ __launch_bounds__(256) void chamfer_partial(
    const float* __restrict__ X,   // output_points [8][4096][3]
    const float* __restrict__ Y,   // target_points [8][4096][3]
    unsigned int* __restrict__ rowmin)   // [NS2][Nn], init 0x7F7F7F7F
{
    constexpr int ATILE = APT * 256;

    __shared__ float4 ldsB[BCHUNK];

    const int at    = blockIdx.x;
    const int bc    = blockIdx.y;
    const int z     = blockIdx.z;
    const int slice = z & 7;
    const int dir   = z >> 3;
    const int tid   = threadIdx.x;

    const float* A  = (dir == 0 ? X : Y) + (size_t)slice * (Nn * 3);
    const float* Bp = (dir == 0 ? Y : X) + (size_t)slice * (Mn * 3) + bc * (BCHUNK * 3);

    // Register-block APT A-points (strided ownership: n = at*ATILE + j*256 + tid).
    float ax[APT], ay[APT], az[APT], acc[APT];
    #pragma unroll
    for (int j = 0; j < APT; ++j) {
        const int n = at * ATILE + j * 256 + tid;
        ax[j] = A[n * 3 + 0];
        ay[j] = A[n * 3 + 1];
        az[j] = A[n * 3 + 2];
        acc[j] = 3.4e38f;
    }

    // Stage B chunk pre-transformed: (-2bx, -2by, -2bz, |b|^2)
    for (int p = tid; p < BCHUNK; p += 256) {
        float bx = Bp[p * 3 + 0], by = Bp[p * 3 + 1], bz = Bp[p * 3 + 2];
        ldsB[p] = make_float4(-2.0f * bx, -2.0f * by, -2.0f * bz,
                              bx * bx + by * by + bz * bz);
    }
    __syncthreads();

    // R3-proven inner loop: 2 ds_read_b128 broadcasts per 2*APT pairs;
    // 3 FMA per pair + v_min3 per 2 pairs, unroll 4.
    #pragma unroll 4
    for (int m = 0; m < BCHUNK; m += 2) {
        const float4 b0 = ldsB[m + 0];
        const float4 b1 = ldsB[m + 1];
        #pragma unroll
        for (int j = 0; j < APT; ++j) {
            float d0 = fmaf(ax[j], b0.x, fmaf(ay[j], b0.y, fmaf(az[j], b0.z, b0.w)));
            float d1 = fmaf(ax[j], b1.x, fmaf(ay[j], b1.y, fmaf(az[j], b1.z, b1.w)));
            acc[j] = fminf(fminf(acc[j], d0), d1);   // -> v_min3_f32
        }
    }

    // Epilogue: full distance (+|a|^2, clamp >=0 so uint-bit order == float
    // order), then device-scope uint atomicMin (order-independent => exact
    // bit-determinism across replays). Replaces the 16 MB pmin round-trip.
    unsigned int* dst = rowmin + (size_t)z * Nn + at * ATILE;
    #pragma unroll
    for (int j = 0; j < APT; ++j) {
        const float a2 = ax[j] * ax[j] + ay[j] * ay[j] + az[j] * az[j];
        const float d  = fmaxf(acc[j] + a2, 0.0f);
        atomicMin(&dst[j * 256 + tid], __float_as_uint(d));
    }
}

__global__ __launch_bounds__(256) void chamfer_rowsum(
    const unsigned int* __restrict__ rowmin, float* __restrict__ sums)  // sums[NS2]
{
    const int z   = blockIdx.x;       // 0..15
    const int tid = threadIdx.x;
    const unsigned int* p = rowmin + (size_t)z * Nn;

    float s = 0.0f;
    #pragma unroll
    for (int i = tid; i < Nn; i += 256) s += __uint_as_float(p[i]);

    // Deterministic reduction: shuffle tree + fixed-order wave combine
    s += __shfl_down(s, 32);
    s += __shfl_down(s, 16);
    s += __shfl_down(s, 8);
    s += __shfl_down(s, 4);
    s += __shfl_down(s, 2);
    s += __shfl_down(s, 1);

    __shared__ float red[4];
    if ((tid & 63) == 0) red[tid >> 6] = s;
    __syncthreads();
    if (tid == 0) sums[z] = red[0] + red[1] + red[2] + red[3];
}

__global__ __launch_bounds__(64) void chamfer_finalize(
    const float* __restrict__ sums, float* __restrict__ out)
{
    const int tid = threadIdx.x;
    // sums[z]: z = dir*8 + (b*4 + s), total min-dist sum for that direction/slice
    // out[0..3]  = chamfer_distances[s] = mean_b combined[b][s]
    // out[4..11] = chamfer_distances_tensor[s][b] = combined[b][s]
    if (tid < 8) {
        const int s = tid >> 1, b = tid & 1;
        const int l = b * Sn + s;
        out[4 + s * 2 + b] = sums[l] * (1.0f / Nn) + sums[8 + l] * (1.0f / Mn);
    } else if (tid < 12) {
        const int s = tid - 8;
        float c0 = sums[0 * Sn + s] * (1.0f / Nn) + sums[8 + 0 * Sn + s] * (1.0f / Mn);
        float c1 = sums[1 * Sn + s] * (1.0f / Nn) + sums[8 + 1 * Sn + s] * (1.0f / Mn);
        out[s] = 0.5f * (c0 + c1);
    }
}

extern "C" void kernel_launch(void* const* d_in, const int* in_sizes, int n_in,
                              void* d_out, int out_size, void* d_ws, size_t ws_size,
                              hipStream_t stream) {
    const float* X = (const float*)d_in[0];   // output_points [2,4,4096,3]
    const float* Y = (const float*)d_in[1];   // target_points [2,4,4096,3]
    float* out = (float*)d_out;               // 12 floats

    unsigned int* rowmin = (unsigned int*)d_ws;            // [16][4096] uints
    float* sums = (float*)(rowmin + (size_t)NS2 * Nn);     // [16]

    // Init mins to 0x7F7F7F7F (3.39e38 as float) every call — required for
    // replay determinism (harness does not re-poison between replays).
    hipMemsetAsync(rowmin, 0x7F, (size_t)NS2 * Nn * sizeof(unsigned int), stream);

    // R3-anchor geometry: grid (2, 32, 16) = 1024 blocks (4/CU), 256 threads.
    dim3 grid(Nn / (APT * 256), NBC, NS2);
    chamfer_partial<<<grid, 256, 0, stream>>>(X, Y, rowmin);
    chamfer_rowsum<<<NS2, 256, 0, stream>>>(rowmin, sums);
    chamfer_finalize<<<1, 64, 0, stream>>>(sums, out);
}

// Round 12
// 36.251 us; speedup vs baseline: 1.7462x; 1.0140x over previous
//
#include <hip/hip_runtime.h>

// Problem constants: B=2, S=4, N=M=4096, fp32 3D points.
constexpr int Sn = 4;
constexpr int Nn = 4096;
constexpr int NS2 = 16;               // z = pass*8 + slice ; pass0 = dist1 (rows=X)

typedef __attribute__((ext_vector_type(8))) short short8v;   // 8 bf16
typedef __attribute__((ext_vector_type(4))) float f32x4;

// ws layout (float4 units):
//   Apack[2][8][4096][2]  (131072 float4, 2 MB)
//   Bpack[2][8][4096][2]  (131072 float4, 2 MB)
//   rowhalf[2][16][4096]  (float, 512 KB)
//   sums2[16*8]           (float)
constexpr size_t PACK_F4 = (size_t)2 * 8 * 4096 * 2;

__device__ inline unsigned short f2bf(float x) {              // RNE fp32->bf16
    unsigned int u = __float_as_uint(x);
    unsigned int r = u + 0x7FFFu + ((u >> 16) & 1u);
    return (unsigned short)(r >> 16);
}
__device__ inline float bf2f(unsigned short h) {
    return __uint_as_float(((unsigned int)h) << 16);
}
__device__ inline float4 pack8(unsigned short s0, unsigned short s1, unsigned short s2,
                               unsigned short s3, unsigned short s4, unsigned short s5,
                               unsigned short s6, unsigned short s7) {
    union { unsigned short s[8]; float4 v; } u;
    u.s[0]=s0; u.s[1]=s1; u.s[2]=s2; u.s[3]=s3;
    u.s[4]=s4; u.s[5]=s5; u.s[6]=s6; u.s[7]=s7;
    return u.v;
}

// ---- prep: per point, hi/lo bf16 split + norm; build A-side and B-side K-slot packs.
// K-slot scheme per 16x16x32 MFMA (k-groups g=lane>>4, 8 slots each; g2,g3 zero):
//   A g0: [ahi x,y,z, alo x,y,z, n2hi, n2lo]      B g0: [-2bhi x,y,z, -2bhi x,y,z, 1, 1]
//   A g1: [ahi x,y,z, alo x,y,z, 1,    1   ]      B g1: [-2blo x,y,z, -2blo x,y,z, m2hi, m2lo]
// sum_k A*B = |a|^2 + |b|^2 - 2*(ahi+alo)·(bhi+blo) = d  (err ~<5e-4)
__global__ __launch_bounds__(256) void chamfer_pack(
    const float* __restrict__ X, const float* __restrict__ Y,
    float4* __restrict__ Apack, float4* __restrict__ Bpack)
{
    const int idx  = blockIdx.x * 256 + threadIdx.x;  // side*32768 + slice*4096 + pt
    const int side = idx >> 15;
    const int rem  = idx & 32767;
    const float* src = (side == 0 ? X : Y) + (size_t)rem * 3;
    const float x = src[0], y = src[1], z = src[2];

    const unsigned short hx = f2bf(x), hy = f2bf(y), hz = f2bf(z);
    const float fx = bf2f(hx), fy = bf2f(hy), fz = bf2f(hz);
    const unsigned short lx = f2bf(x - fx), ly = f2bf(y - fy), lz = f2bf(z - fz);
    const float n2 = x * x + y * y + z * z;
    const unsigned short n2h = f2bf(n2);
    const unsigned short n2l = f2bf(n2 - bf2f(n2h));
    const unsigned short one = 0x3F80;
    // -2*(bf16) is exact in bf16 (sign flip + exp+1)
    const unsigned short mhx = f2bf(-2.0f * bf2f(hx)), mhy = f2bf(-2.0f * bf2f(hy)),
                         mhz = f2bf(-2.0f * bf2f(hz));
    const unsigned short mlx = f2bf(-2.0f * bf2f(lx)), mly = f2bf(-2.0f * bf2f(ly)),
                         mlz = f2bf(-2.0f * bf2f(lz));

    const size_t base = (size_t)idx * 2;
    Apack[base + 0] = pack8(hx, hy, hz, lx, ly, lz, n2h, n2l);
    Apack[base + 1] = pack8(hx, hy, hz, lx, ly, lz, one, one);
    Bpack[base + 0] = pack8(mhx, mhy, mhz, mhx, mhy, mhz, one, one);
    Bpack[base + 1] = pack8(mlx, mly, mlz, mlx, mly, mlz, n2h, n2l);
}

// ---- main: one MFMA per 16x16 d-tile; row-mins in regs; 2 passes via blockIdx.z.
// Block: 4 waves x 32 rows = 128 rows; sweeps half the cols (2048) via 2 LDS chunks.
__global__ __launch_bounds__(256) void chamfer_mfma(
    const float4* __restrict__ Apack, const float4* __restrict__ Bpack,
    float* __restrict__ rowhalf)      // [2][16][4096]
{
    const int band = blockIdx.x;      // 0..31  (128-row band)
    const int half = blockIdx.y;      // 0..1   (2048-col half)
    const int zz   = blockIdx.z;      // 0..15  (pass*8 + slice)
    const int p    = zz >> 3;
    const int slice= zz & 7;
    const int tid  = threadIdx.x;
    const int w    = tid >> 6;        // wave 0..3
    const int cc   = tid & 15;        // A-row / B-col lane index
    const int cg   = (tid & 63) >> 4; // k-group 0..3
    const bool act = (cg < 2);        // only groups 0,1 carry data

    const float4* Ap = Apack + ((size_t)(p * 8 + slice) * 4096) * 2;        // A side = pass
    const float4* Bp = Bpack + ((size_t)((1 - p) * 8 + slice) * 4096) * 2;  // B side = other

    // A fragments for this wave's two row-tiles (loaded once)
    short8v a0 = {0,0,0,0,0,0,0,0}, a1 = {0,0,0,0,0,0,0,0};
    const int r0 = band * 128 + w * 32 + cc;
    if (act) {
        float4 t0 = Ap[(size_t)r0 * 2 + cg];
        float4 t1 = Ap[(size_t)(r0 + 16) * 2 + cg];
        a0 = *(short8v*)&t0;
        a1 = *(short8v*)&t1;
    }

    __shared__ float4 lds[2][1024];   // [g][col] B-frags for a 1024-col chunk (32 KB)

    f32x4 rmin0, rmin1;
    rmin0[0]=rmin0[1]=rmin0[2]=rmin0[3]=3.4e38f;
    rmin1[0]=rmin1[1]=rmin1[2]=rmin1[3]=3.4e38f;

    for (int chunk = 0; chunk < 2; ++chunk) {
        const int colbase = half * 2048 + chunk * 1024;
        if (chunk) __syncthreads();
        for (int i = tid; i < 2048; i += 256) {
            const int col = i >> 1, g = i & 1;
            lds[g][col] = Bp[(size_t)(colbase + col) * 2 + g];
        }
        __syncthreads();

        #pragma unroll 4
        for (int step = 0; step < 64; ++step) {
            short8v bf = {0,0,0,0,0,0,0,0};
            if (act) {                       // exec-masked: half-wave ds_read_b128
                float4 t = lds[cg][step * 16 + cc];
                bf = *(short8v*)&t;
            }
            const f32x4 zero = {0.0f, 0.0f, 0.0f, 0.0f};
            // D[4*cg+reg][cc] = d-tile element, finished (norms folded into K-slots)
            f32x4 acc0 = __builtin_amdgcn_mfma_f32_16x16x32_bf16(a0, bf, zero, 0, 0, 0);
            f32x4 acc1 = __builtin_amdgcn_mfma_f32_16x16x32_bf16(a1, bf, zero, 0, 0, 0);
            rmin0[0]=fminf(rmin0[0],acc0[0]); rmin0[1]=fminf(rmin0[1],acc0[1]);
            rmin0[2]=fminf(rmin0[2],acc0[2]); rmin0[3]=fminf(rmin0[3],acc0[3]);
            rmin1[0]=fminf(rmin1[0],acc1[0]); rmin1[1]=fminf(rmin1[1],acc1[1]);
            rmin1[2]=fminf(rmin1[2],acc1[2]); rmin1[3]=fminf(rmin1[3],acc1[3]);
        }
    }

    // Row-min: reduce across the 16 cc-lanes (xor shuffles stay in 16-lane group)
    #pragma unroll
    for (int off = 1; off <= 8; off <<= 1) {
        rmin0[0]=fminf(rmin0[0],__shfl_xor(rmin0[0],off)); rmin0[1]=fminf(rmin0[1],__shfl_xor(rmin0[1],off));
        rmin0[2]=fminf(rmin0[2],__shfl_xor(rmin0[2],off)); rmin0[3]=fminf(rmin0[3],__shfl_xor(rmin0[3],off));
        rmin1[0]=fminf(rmin1[0],__shfl_xor(rmin1[0],off)); rmin1[1]=fminf(rmin1[1],__shfl_xor(rmin1[1],off));
        rmin1[2]=fminf(rmin1[2],__shfl_xor(rmin1[2],off)); rmin1[3]=fminf(rmin1[3],__shfl_xor(rmin1[3],off));
    }
    if (cc == 0) {   // exclusive writer per (row, half): deterministic plain stores
        float* dst = rowhalf + ((size_t)half * NS2 + zz) * Nn + band * 128 + w * 32;
        #pragma unroll
        for (int r = 0; r < 4; ++r) {
            dst[4 * cg + r]      = rmin0[r];   // tile0 rows +0..15
            dst[16 + 4 * cg + r] = rmin1[r];   // tile1 rows +16..31
        }
    }
}

__global__ __launch_bounds__(256) void chamfer_rowsum(
    const float* __restrict__ rowhalf, float* __restrict__ sums2)  // sums2[16][8]
{
    const int z   = blockIdx.x;       // 0..15
    const int c   = blockIdx.y;       // 0..7
    const int tid = threadIdx.x;
    const float* p0 = rowhalf + (size_t)z * Nn;              // half 0
    const float* p1 = rowhalf + (size_t)(NS2 + z) * Nn;      // half 1

    float s = 0.0f;
    for (int i = c * 512 + tid; i < (c + 1) * 512; i += 256)
        s += fminf(p0[i], p1[i]);

    s += __shfl_down(s, 32); s += __shfl_down(s, 16); s += __shfl_down(s, 8);
    s += __shfl_down(s, 4);  s += __shfl_down(s, 2);  s += __shfl_down(s, 1);

    __shared__ float red[4];
    if ((tid & 63) == 0) red[tid >> 6] = s;
    __syncthreads();
    if (tid == 0) sums2[z * 8 + c] = red[0] + red[1] + red[2] + red[3];
}

__global__ __launch_bounds__(64) void chamfer_finalize(
    const float* __restrict__ sums2, float* __restrict__ out)
{
    const int tid = threadIdx.x;
    __shared__ float tot[NS2];
    if (tid < NS2) {
        float t = 0.0f;
        #pragma unroll
        for (int c = 0; c < 8; ++c) t += sums2[tid * 8 + c];
        tot[tid] = t;
    }
    __syncthreads();
    // tot[z]: z = pass*8 + (b*4 + s); combined[b][s] = tot[l]/N + tot[8+l]/M
    if (tid < 8) {
        const int s = tid >> 1, b = tid & 1;
        const int l = b * Sn + s;
        out[4 + s * 2 + b] = tot[l] * (1.0f / Nn) + tot[8 + l] * (1.0f / Nn);
    } else if (tid < 12) {
        const int s = tid - 8;
        float c0 = tot[0 * Sn + s] * (1.0f / Nn) + tot[8 + 0 * Sn + s] * (1.0f / Nn);
        float c1 = tot[1 * Sn + s] * (1.0f / Nn) + tot[8 + 1 * Sn + s] * (1.0f / Nn);
        out[s] = 0.5f * (c0 + c1);
    }
}

extern "C" void kernel_launch(void* const* d_in, const int* in_sizes, int n_in,
                              void* d_out, int out_size, void* d_ws, size_t ws_size,
                              hipStream_t stream) {
    const float* X = (const float*)d_in[0];   // output_points [2,4,4096,3]
    const float* Y = (const float*)d_in[1];   // target_points [2,4,4096,3]
    float* out = (float*)d_out;               // 12 floats

    float4* Apack  = (float4*)d_ws;
    float4* Bpack  = Apack + PACK_F4;
    float* rowhalf = (float*)(Bpack + PACK_F4);          // [2][16][4096]
    float* sums2   = rowhalf + (size_t)2 * NS2 * Nn;     // [16][8]

    chamfer_pack<<<65536 / 256, 256, 0, stream>>>(X, Y, Apack, Bpack);
    chamfer_mfma<<<dim3(32, 2, NS2), 256, 0, stream>>>(Apack, Bpack, rowhalf);
    chamfer_rowsum<<<dim3(NS2, 8), 256, 0, stream>>>(rowhalf, sums2);
    chamfer_finalize<<<1, 64, 0, stream>>>(sums2, out);
}